// Round 2
// 266.307 us; speedup vs baseline: 1.0258x; 1.0258x over previous
//
#include <hip/hip_runtime.h>
#include <math.h>

#define DDIM 4096
#define NTOK 8192

typedef float nfloat4 __attribute__((ext_vector_type(4)));

__device__ __forceinline__ float softplus_f(float r) {
  return (r > 0.0f) ? (r + log1pf(__expf(-r))) : log1pf(__expf(r));
}

// ---------------------------------------------------------------------------
// Layout B element index for (lane l in 0..255, reg u in 0..15):
//   i = ((l>>6)<<10) | (u<<6) | ((l&15)<<2) | ((l&63)>>4)
// gt_perm storage is arranged so the main kernel's 4 float4 g-loads are
// perfectly coalesced:  gt_perm[a*1024 + l*4 + b] = g_tilde[i(l, u=4a+b)]
// ---------------------------------------------------------------------------
__global__ __launch_bounds__(256) void gt_perm_kernel(
    const float* __restrict__ g_mu, const float* __restrict__ g_rho,
    const float* __restrict__ eps, float* __restrict__ gt_perm)
{
  int j = blockIdx.x * 256 + threadIdx.x;   // 0..4095
  int a = j >> 10, l = (j >> 2) & 255, b = j & 3;
  int u = 4 * a + b;
  int t = l & 63;
  int i = ((l >> 6) << 10) + (u << 6) + ((t & 15) << 2) + (t >> 4);
  gt_perm[j] = g_mu[i] + softplus_f(g_rho[i]) * eps[i];
}

// ---- cross-lane butterfly helpers (lane-bit FWHT stages) -------------------
// x' = fma(x, sgn, partner): bit==0 lanes compute a+b, bit==1 lanes b-a.
__device__ __forceinline__ float bfly_dpp_x1(float x, float sgn) {
  // quad_perm [1,0,3,2] = 0xB1 -> partner lane^1 (VALU, no DS traffic)
  float p = __int_as_float(__builtin_amdgcn_mov_dpp(__float_as_int(x), 0xB1, 0xF, 0xF, true));
  return fmaf(x, sgn, p);
}
__device__ __forceinline__ float bfly_dpp_x2(float x, float sgn) {
  // quad_perm [2,3,0,1] = 0x4E -> partner lane^2
  float p = __int_as_float(__builtin_amdgcn_mov_dpp(__float_as_int(x), 0x4E, 0xF, 0xF, true));
  return fmaf(x, sgn, p);
}
__device__ __forceinline__ float bfly_sw_x4(float x, float sgn) {
  // ds_swizzle BitMode: (xor<<10)|(or<<5)|and ; xor=4, and=0x1F
  float p = __int_as_float(__builtin_amdgcn_ds_swizzle(__float_as_int(x), 0x101F));
  return fmaf(x, sgn, p);
}
__device__ __forceinline__ float bfly_sw_x8(float x, float sgn) {
  float p = __int_as_float(__builtin_amdgcn_ds_swizzle(__float_as_int(x), 0x201F));
  return fmaf(x, sgn, p);
}

// 4-bit FWHT over the 16 per-lane registers (whatever bits they carry).
__device__ __forceinline__ void fwht16(float w[16]) {
#pragma unroll
  for (int m = 1; m < 16; m <<= 1) {
#pragma unroll
    for (int k = 0; k < 16; ++k) {
      if ((k & m) == 0) {
        float a = w[k], b = w[k ^ m];
        w[k]     = a + b;
        w[k ^ m] = a - b;
      }
    }
  }
}

// FWHT over lane bits t0..t3 (= element bits i[2..5] in BOTH layouts).
__device__ __forceinline__ void fwht_lane4(float w[16], float sg1, float sg2,
                                           float sg4, float sg8) {
#pragma unroll
  for (int k = 0; k < 16; ++k) w[k] = bfly_dpp_x1(w[k], sg1);
#pragma unroll
  for (int k = 0; k < 16; ++k) w[k] = bfly_dpp_x2(w[k], sg2);
#pragma unroll
  for (int k = 0; k < 16; ++k) w[k] = bfly_sw_x4(w[k], sg4);
#pragma unroll
  for (int k = 0; k < 16; ++k) w[k] = bfly_sw_x8(w[k], sg8);
}

// ---------------------------------------------------------------------------
// One row per 256-thread block (4 waves). 16 floats/lane.
// Layout A: element i = c*1024 + 4*l + r held in w[4c+r]      (c=i[11:10], r=i[1:0])
// Layout B: element i = rbase + 64*u held in w[u]             (u=i[9:6])
// Pass = fwht16(A-bits) + fwht_lane4(i[5:2]) + LDS transpose + fwht16(B-bits).
// LDS 16 KB -> 8 blocks/CU (wave cap) = 32 waves/CU; launch_bounds caps VGPR
// at 64 so occupancy is LDS/wave-slot limited, not VGPR limited.
// ---------------------------------------------------------------------------
template <bool USE_WS>
__global__ __launch_bounds__(256, 8) void whvi_kernel(
    const float* __restrict__ x,
    const float* __restrict__ s1v,
    const float* __restrict__ s2v,
    const float* __restrict__ gt_perm,   // USE_WS path
    const float* __restrict__ g_mu,      // fallback path
    const float* __restrict__ g_rho,
    const float* __restrict__ eps,
    float* __restrict__ out)
{
  __shared__ __align__(16) float L[DDIM];   // 16384 B

  const int l = threadIdx.x;                // 0..255
  const int t = l & 63;
  const size_t row = (size_t)blockIdx.x;

  const float sg1 = (t & 1) ? -1.0f : 1.0f;
  const float sg2 = (t & 2) ? -1.0f : 1.0f;
  const float sg4 = (t & 4) ? -1.0f : 1.0f;
  const float sg8 = (t & 8) ? -1.0f : 1.0f;

  float w[16];

  // ---- load x row (4x b128, coalesced) and multiply by s2 (L2-hot) ----
  const float4* x4  = (const float4*)x + row * (DDIM / 4);
  const float4* s24 = (const float4*)s2v;
#pragma unroll
  for (int c = 0; c < 4; ++c) {
    float4 a = x4[256 * c + l];
    float4 b = s24[256 * c + l];
    w[4 * c + 0] = a.x * b.x;
    w[4 * c + 1] = a.y * b.y;
    w[4 * c + 2] = a.z * b.z;
    w[4 * c + 3] = a.w * b.w;
  }

  // ---- FWHT pass 1 ----
  fwht16(w);                            // bits {i11,i10,i1,i0}
  fwht_lane4(w, sg1, sg2, sg4, sg8);    // bits {i2,i3,i4,i5}

  // exchange A -> B: b128 writes (conflict-free), b32 reads (2-way = free)
#pragma unroll
  for (int c = 0; c < 4; ++c)
    *(float4*)&L[1024 * c + 4 * l] =
        make_float4(w[4 * c + 0], w[4 * c + 1], w[4 * c + 2], w[4 * c + 3]);
  __syncthreads();
  const int rbase = ((l >> 6) << 10) + ((t & 15) << 2) + (t >> 4);
#pragma unroll
  for (int u = 0; u < 16; ++u) w[u] = L[rbase + 64 * u];

  fwht16(w);                            // bits {i9,i8,i7,i6} -> pass 1 done

  // ---- multiply by g_tilde (layout B) ----
  if (USE_WS) {
    const float4* g4 = (const float4*)gt_perm;
#pragma unroll
    for (int a = 0; a < 4; ++a) {       // coalesced: lane l reads float4 a*256+l
      float4 g = g4[256 * a + l];
      w[4 * a + 0] *= g.x;
      w[4 * a + 1] *= g.y;
      w[4 * a + 2] *= g.z;
      w[4 * a + 3] *= g.w;
    }
  } else {
#pragma unroll
    for (int u = 0; u < 16; ++u) {
      int i = rbase + 64 * u;           // rbase+64u IS the element index
      float g = g_mu[i] + softplus_f(g_rho[i]) * eps[i];
      w[u] *= g;
    }
  }

  // ---- FWHT pass 2 ----
  fwht16(w);                            // bits {i9,i8,i7,i6}
  fwht_lane4(w, sg1, sg2, sg4, sg8);    // bits {i2,i3,i4,i5}

  // exchange B -> A (reuse L; barrier protects exchange-1 reads of all waves)
  __syncthreads();
#pragma unroll
  for (int u = 0; u < 16; ++u) L[rbase + 64 * u] = w[u];
  __syncthreads();
#pragma unroll
  for (int c = 0; c < 4; ++c) {
    float4 a = *(const float4*)&L[1024 * c + 4 * l];
    w[4 * c + 0] = a.x;
    w[4 * c + 1] = a.y;
    w[4 * c + 2] = a.z;
    w[4 * c + 3] = a.w;
  }
  fwht16(w);                            // bits {i11,i10,i1,i0} -> pass 2 done

  // ---- multiply by s1, store coalesced; nt-store keeps x resident in L3 ----
  const float4* s14 = (const float4*)s1v;
  float4* out4 = (float4*)out + row * (DDIM / 4);
#pragma unroll
  for (int c = 0; c < 4; ++c) {
    float4 b = s14[256 * c + l];
    nfloat4 v = { w[4 * c + 0] * b.x, w[4 * c + 1] * b.y,
                  w[4 * c + 2] * b.z, w[4 * c + 3] * b.w };
    __builtin_nontemporal_store(v, (nfloat4*)&out4[256 * c + l]);
  }
}

extern "C" void kernel_launch(void* const* d_in, const int* in_sizes, int n_in,
                              void* d_out, int out_size, void* d_ws, size_t ws_size,
                              hipStream_t stream) {
  const float* x     = (const float*)d_in[0];
  const float* s1    = (const float*)d_in[1];
  const float* s2    = (const float*)d_in[2];
  const float* g_mu  = (const float*)d_in[3];
  const float* g_rho = (const float*)d_in[4];
  const float* eps   = (const float*)d_in[5];
  float* out = (float*)d_out;

  if (ws_size >= DDIM * sizeof(float)) {
    float* gt_perm = (float*)d_ws;
    gt_perm_kernel<<<DDIM / 256, 256, 0, stream>>>(g_mu, g_rho, eps, gt_perm);
    whvi_kernel<true><<<NTOK, 256, 0, stream>>>(
        x, s1, s2, gt_perm, nullptr, nullptr, nullptr, out);
  } else {
    whvi_kernel<false><<<NTOK, 256, 0, stream>>>(
        x, s1, s2, nullptr, g_mu, g_rho, eps, out);
  }
}

// Round 3
// 265.934 us; speedup vs baseline: 1.0272x; 1.0014x over previous
//
#include <hip/hip_runtime.h>
#include <math.h>

#define DDIM 4096
#define NTOK 8192

typedef float nfloat4 __attribute__((ext_vector_type(4)));

__device__ __forceinline__ float softplus_f(float r) {
  return (r > 0.0f) ? (r + log1pf(__expf(-r))) : log1pf(__expf(r));
}

// ---------------------------------------------------------------------------
// Layout B element index for (lane l in 0..255, reg u in 0..15):
//   i = ((l>>6)<<10) | (u<<6) | ((l&15)<<2) | ((l&63)>>4)
// gt_perm storage is arranged so the main kernel's 4 float4 g-loads are
// perfectly coalesced:  gt_perm[a*1024 + l*4 + b] = g_tilde[i(l, u=4a+b)]
// ---------------------------------------------------------------------------
__global__ __launch_bounds__(256) void gt_perm_kernel(
    const float* __restrict__ g_mu, const float* __restrict__ g_rho,
    const float* __restrict__ eps, float* __restrict__ gt_perm)
{
  int j = blockIdx.x * 256 + threadIdx.x;   // 0..4095
  int a = j >> 10, l = (j >> 2) & 255, b = j & 3;
  int u = 4 * a + b;
  int t = l & 63;
  int i = ((l >> 6) << 10) + (u << 6) + ((t & 15) << 2) + (t >> 4);
  gt_perm[j] = g_mu[i] + softplus_f(g_rho[i]) * eps[i];
}

// ---- cross-lane butterfly helpers (lane-bit FWHT stages) -------------------
// x' = fma(x, sgn, partner): bit==0 lanes compute a+b, bit==1 lanes b-a.
__device__ __forceinline__ float bfly_dpp_x1(float x, float sgn) {
  // quad_perm [1,0,3,2] = 0xB1 -> partner lane^1 (VALU, no DS traffic)
  float p = __int_as_float(__builtin_amdgcn_mov_dpp(__float_as_int(x), 0xB1, 0xF, 0xF, true));
  return fmaf(x, sgn, p);
}
__device__ __forceinline__ float bfly_dpp_x2(float x, float sgn) {
  // quad_perm [2,3,0,1] = 0x4E -> partner lane^2
  float p = __int_as_float(__builtin_amdgcn_mov_dpp(__float_as_int(x), 0x4E, 0xF, 0xF, true));
  return fmaf(x, sgn, p);
}
__device__ __forceinline__ float bfly_sw_x4(float x, float sgn) {
  // ds_swizzle BitMode: (xor<<10)|(or<<5)|and ; xor=4, and=0x1F
  float p = __int_as_float(__builtin_amdgcn_ds_swizzle(__float_as_int(x), 0x101F));
  return fmaf(x, sgn, p);
}
__device__ __forceinline__ float bfly_dpp_x8(float x, float sgn) {
  // row_ror:8 = dpp_ctrl 0x128: within a 16-lane row, rotate by 8 == lane^8
  // (rotation by half the row is an involution). Pure VALU — no DS traffic,
  // no lgkmcnt wait. Replaces ds_swizzle 0x201F.
  float p = __int_as_float(__builtin_amdgcn_mov_dpp(__float_as_int(x), 0x128, 0xF, 0xF, true));
  return fmaf(x, sgn, p);
}

// 4-bit FWHT over the 16 per-lane registers (whatever bits they carry).
__device__ __forceinline__ void fwht16(float w[16]) {
#pragma unroll
  for (int m = 1; m < 16; m <<= 1) {
#pragma unroll
    for (int k = 0; k < 16; ++k) {
      if ((k & m) == 0) {
        float a = w[k], b = w[k ^ m];
        w[k]     = a + b;
        w[k ^ m] = a - b;
      }
    }
  }
}

// FWHT over lane bits t0..t3 (= element bits i[2..5] in BOTH layouts).
// Stage order: the xor4 ds_swizzle stage is issued first so its LDS-pipe
// latency overlaps the three pure-VALU DPP stages that follow.
__device__ __forceinline__ void fwht_lane4(float w[16], float sg1, float sg2,
                                           float sg4, float sg8) {
#pragma unroll
  for (int k = 0; k < 16; ++k) w[k] = bfly_sw_x4(w[k], sg4);
#pragma unroll
  for (int k = 0; k < 16; ++k) w[k] = bfly_dpp_x1(w[k], sg1);
#pragma unroll
  for (int k = 0; k < 16; ++k) w[k] = bfly_dpp_x2(w[k], sg2);
#pragma unroll
  for (int k = 0; k < 16; ++k) w[k] = bfly_dpp_x8(w[k], sg8);
}

// ---------------------------------------------------------------------------
// One row per 256-thread block (4 waves). 16 floats/lane.
// Layout A: element i = c*1024 + 4*l + r held in w[4c+r]      (c=i[11:10], r=i[1:0])
// Layout B: element i = rbase + 64*u held in w[u]             (u=i[9:6])
// Pass = fwht16(A-bits) + fwht_lane4(i[5:2]) + LDS transpose + fwht16(B-bits).
// LDS 16 KB -> 8 blocks/CU (wave-slot cap) = 32 waves/CU; launch_bounds caps
// VGPR at 64 so occupancy is wave-slot limited, not VGPR limited.
// ---------------------------------------------------------------------------
template <bool USE_WS>
__global__ __launch_bounds__(256, 8) void whvi_kernel(
    const float* __restrict__ x,
    const float* __restrict__ s1v,
    const float* __restrict__ s2v,
    const float* __restrict__ gt_perm,   // USE_WS path
    const float* __restrict__ g_mu,      // fallback path
    const float* __restrict__ g_rho,
    const float* __restrict__ eps,
    float* __restrict__ out)
{
  __shared__ __align__(16) float L[DDIM];   // 16384 B

  const int l = threadIdx.x;                // 0..255
  const int t = l & 63;
  const size_t row = (size_t)blockIdx.x;

  const float sg1 = (t & 1) ? -1.0f : 1.0f;
  const float sg2 = (t & 2) ? -1.0f : 1.0f;
  const float sg4 = (t & 4) ? -1.0f : 1.0f;
  const float sg8 = (t & 8) ? -1.0f : 1.0f;

  float w[16];

  // ---- load x row (4x b128, coalesced) and multiply by s2 (L2-hot) ----
  const float4* x4  = (const float4*)x + row * (DDIM / 4);
  const float4* s24 = (const float4*)s2v;
#pragma unroll
  for (int c = 0; c < 4; ++c) {
    float4 a = x4[256 * c + l];
    float4 b = s24[256 * c + l];
    w[4 * c + 0] = a.x * b.x;
    w[4 * c + 1] = a.y * b.y;
    w[4 * c + 2] = a.z * b.z;
    w[4 * c + 3] = a.w * b.w;
  }

  // ---- FWHT pass 1 ----
  fwht16(w);                            // bits {i11,i10,i1,i0}
  fwht_lane4(w, sg1, sg2, sg4, sg8);    // bits {i2,i3,i4,i5}

  // exchange A -> B: b128 writes (conflict-free), b32 reads (2-way = free)
#pragma unroll
  for (int c = 0; c < 4; ++c)
    *(float4*)&L[1024 * c + 4 * l] =
        make_float4(w[4 * c + 0], w[4 * c + 1], w[4 * c + 2], w[4 * c + 3]);
  __syncthreads();
  const int rbase = ((l >> 6) << 10) + ((t & 15) << 2) + (t >> 4);
#pragma unroll
  for (int u = 0; u < 16; ++u) w[u] = L[rbase + 64 * u];

  fwht16(w);                            // bits {i9,i8,i7,i6} -> pass 1 done

  // ---- multiply by g_tilde (layout B) ----
  if (USE_WS) {
    const float4* g4 = (const float4*)gt_perm;
#pragma unroll
    for (int a = 0; a < 4; ++a) {       // coalesced: lane l reads float4 a*256+l
      float4 g = g4[256 * a + l];
      w[4 * a + 0] *= g.x;
      w[4 * a + 1] *= g.y;
      w[4 * a + 2] *= g.z;
      w[4 * a + 3] *= g.w;
    }
  } else {
#pragma unroll
    for (int u = 0; u < 16; ++u) {
      int i = rbase + 64 * u;           // rbase+64u IS the element index
      float g = g_mu[i] + softplus_f(g_rho[i]) * eps[i];
      w[u] *= g;
    }
  }

  // ---- FWHT pass 2 ----
  fwht16(w);                            // bits {i9,i8,i7,i6}
  fwht_lane4(w, sg1, sg2, sg4, sg8);    // bits {i2,i3,i4,i5}

  // exchange B -> A (reuse L; barrier protects exchange-1 reads of all waves)
  __syncthreads();
#pragma unroll
  for (int u = 0; u < 16; ++u) L[rbase + 64 * u] = w[u];
  __syncthreads();
#pragma unroll
  for (int c = 0; c < 4; ++c) {
    float4 a = *(const float4*)&L[1024 * c + 4 * l];
    w[4 * c + 0] = a.x;
    w[4 * c + 1] = a.y;
    w[4 * c + 2] = a.z;
    w[4 * c + 3] = a.w;
  }
  fwht16(w);                            // bits {i11,i10,i1,i0} -> pass 2 done

  // ---- multiply by s1, store coalesced; nt-store keeps x resident in L3 ----
  const float4* s14 = (const float4*)s1v;
  float4* out4 = (float4*)out + row * (DDIM / 4);
#pragma unroll
  for (int c = 0; c < 4; ++c) {
    float4 b = s14[256 * c + l];
    nfloat4 v = { w[4 * c + 0] * b.x, w[4 * c + 1] * b.y,
                  w[4 * c + 2] * b.z, w[4 * c + 3] * b.w };
    __builtin_nontemporal_store(v, (nfloat4*)&out4[256 * c + l]);
  }
}

extern "C" void kernel_launch(void* const* d_in, const int* in_sizes, int n_in,
                              void* d_out, int out_size, void* d_ws, size_t ws_size,
                              hipStream_t stream) {
  const float* x     = (const float*)d_in[0];
  const float* s1    = (const float*)d_in[1];
  const float* s2    = (const float*)d_in[2];
  const float* g_mu  = (const float*)d_in[3];
  const float* g_rho = (const float*)d_in[4];
  const float* eps   = (const float*)d_in[5];
  float* out = (float*)d_out;

  if (ws_size >= DDIM * sizeof(float)) {
    float* gt_perm = (float*)d_ws;
    gt_perm_kernel<<<DDIM / 256, 256, 0, stream>>>(g_mu, g_rho, eps, gt_perm);
    whvi_kernel<true><<<NTOK, 256, 0, stream>>>(
        x, s1, s2, gt_perm, nullptr, nullptr, nullptr, out);
  } else {
    whvi_kernel<false><<<NTOK, 256, 0, stream>>>(
        x, s1, s2, nullptr, g_mu, g_rho, eps, out);
  }
}